// Round 1
// baseline (42.129 us; speedup 1.0000x reference)
//
#include <hip/hip_runtime.h>

// Unfold (B,C,H,W,D)=(8,16,64,64,64), kernel=stride=(4,4,4)  -> (B,C,4,4,4,4096)
// Pure permutation: 128 MiB in + 128 MiB out. Memory-bound.
//
// Per (b,c):  out[(i*4+j)*4+k][ph*256+pw*16+pd] = in[4ph+i][4pw+j][4pd+k]
// Linear float4 index t over input decomposes as (bc, h, w, pd) in memory
// order -> coalesced float4 reads. 4 scalar stores/thread, each wave store
// instruction covers 4 full 64B lines (lanes 0..15 write pd=0..15 contiguous).

__global__ __launch_bounds__(256) void unfold_perm_kernel(
    const float4* __restrict__ in4, float* __restrict__ out) {
    unsigned t = blockIdx.x * 256u + threadIdx.x;   // exact grid, no bounds check

    float4 v = in4[t];                              // fully coalesced 16B/lane

    unsigned pd = t & 15u;          // d / 4
    unsigned w  = (t >> 4) & 63u;   // input w
    unsigned h  = (t >> 10) & 63u;  // input h
    unsigned bc = t >> 16;          // b*16 + c

    unsigned i  = h & 3u, ph = h >> 2;
    unsigned j  = w & 3u, pw = w >> 2;

    unsigned s  = ph * 256u + pw * 16u + pd;            // spatial out index
    unsigned c0 = (i * 4u + j) * 4u;                    // channel base (k=0)

    float* obase = out + ((size_t)bc << 18)             // bc * 64*4096
                       + (size_t)c0 * 4096u + s;

    obase[0]      = v.x;   // k = 0
    obase[4096]   = v.y;   // k = 1
    obase[8192]   = v.z;   // k = 2
    obase[12288]  = v.w;   // k = 3
}

extern "C" void kernel_launch(void* const* d_in, const int* in_sizes, int n_in,
                              void* d_out, int out_size, void* d_ws, size_t ws_size,
                              hipStream_t stream) {
    const float4* in4 = (const float4*)d_in[0];
    float* out = (float*)d_out;

    // total float4s = 8*16*64*64*64 / 4 = 8,388,608 ; 256 threads/block
    const unsigned nThreads = 8u * 16u * 64u * 64u * 16u;  // 8,388,608
    const unsigned nBlocks  = nThreads / 256u;             // 32,768

    unfold_perm_kernel<<<nBlocks, 256, 0, stream>>>(in4, out);
}